// Round 1
// baseline (253.909 us; speedup 1.0000x reference)
//
#include <hip/hip_runtime.h>
#include <math.h>

#define T_LEN 512
#define H_HEADS 8
#define DK 64
#define LR 128      // L_TABLES * R = 8 * 16
#define NTOT 32     // M*B*H
#define TT 64       // t-tile size

__device__ __forceinline__ float fast_tanh(float x) {
    // tanh(x) = 1 - 2/(1+e^{2x}); stable at +-inf via __expf saturation
    float e = __expf(2.0f * x);
    return 1.0f - 2.0f / (1.0f + e);
}

// K1: per (n, t-tile of 64): projections -> tanh/8 -> per-table softmax probs.
// Writes probs TRANSPOSED: p[n][lr][t]  (lr = l*16+r), so k2/k3 reads are coalesced.
__global__ __launch_bounds__(256) void k_probs(
    const float* __restrict__ Khf, const float* __restrict__ Qhf,
    const float* __restrict__ planesT, const float* __restrict__ protosT,
    float* __restrict__ pKT, float* __restrict__ pQT)
{
    __shared__ float sm[14912];            // 58.3 KB
    float* planes = sm;                    // [64][32]   2048
    float* protos = sm + 2048;             // [4][16]    64
    float* xt     = sm + 2112;             // [2][64][32] 4096
    float* XK     = sm + 6208;             // [64][64]   4096
    float* XQ     = sm + 10304;            // [64][64]   4096
    float* pbuf   = sm + 6208;             // [128][68]  8704 (aliases XK/XQ, used after)

    const int bx = blockIdx.x;
    const int n  = bx >> 3;
    const int t0 = (bx & 7) * TT;
    const int g  = n >> 3, h = n & 7;
    const int tid = threadIdx.x;

#pragma unroll
    for (int m = 0; m < 8; ++m) planes[m * 256 + tid] = planesT[m * 256 + tid];
    if (tid < 64) protos[tid] = protosT[tid];
#pragma unroll
    for (int m = 0; m < 16; ++m) {
        int idx = m * 256 + tid;
        int d = idx & 63, tl = idx >> 6;
        long off = ((long)(g * T_LEN + t0 + tl) * H_HEADS + h) * DK + d;
        XK[tl * 64 + d] = Khf[off];
        XQ[tl * 64 + d] = Qhf[off];
    }
    __syncthreads();

    // projections: 4096 dot-products of length 64 (2 sides x 64 t x 32 cols)
#pragma unroll
    for (int w = 0; w < 16; ++w) {
        int task = w * 256 + tid;
        int jj = task & 63, tl = task >> 6;
        int side = jj >> 5, j = jj & 31;
        const float* X = side ? (XQ + tl * 64) : (XK + tl * 64);
        float acc = 0.f;
#pragma unroll 8
        for (int d = 0; d < 64; ++d) acc += X[d] * planes[d * 32 + j];
        xt[(side * 64 + tl) * 32 + j] = fast_tanh(acc) * 0.125f;  // /sqrt(64)
    }
    __syncthreads();

    const int r = tid & 15, l = (tid >> 4) & 7, thi = tid >> 7;
    for (int side = 0; side < 2; ++side) {
        float p0 = protos[r], p1 = protos[16 + r], p2 = protos[32 + r], p3 = protos[48 + r];
#pragma unroll 4
        for (int w = 0; w < 32; ++w) {
            int tl = w * 2 + thi;
            const float* x = xt + (side * 64 + tl) * 32 + l * 4;
            float logit = x[0] * p0 + x[1] * p1 + x[2] * p2 + x[3] * p3;
            // |logit| <= 0.5 -> softmax without max subtraction is safe
            float e = __expf(logit);
            float s = e;
            s += __shfl_xor(s, 1, 16);
            s += __shfl_xor(s, 2, 16);
            s += __shfl_xor(s, 4, 16);
            s += __shfl_xor(s, 8, 16);
            pbuf[(l * 16 + r) * 68 + tl] = e / s;
        }
        __syncthreads();
        float* dst = side ? pQT : pKT;
#pragma unroll 4
        for (int w = 0; w < 32; ++w) {
            int idx = w * 256 + tid;
            int tl = idx & 63, lr = idx >> 6;
            dst[(long)(n * LR + lr) * T_LEN + t0 + tl] = pbuf[lr * 68 + tl];
        }
        __syncthreads();
    }
}

// K2: per (n,lr): causal cumsum of pK over t; qw = pQ/(A+1e-6) in place.
__global__ __launch_bounds__(256) void k_cumsum(
    const float* __restrict__ pKT, float* __restrict__ pQT)
{
    int gid = blockIdx.x * 256 + threadIdx.x;      // 0..4095 = n*128+lr
    long base = (long)gid * T_LEN;
    float A = 0.f;
    for (int t = 0; t < T_LEN; t += 4) {
        float4 k4 = *(const float4*)(pKT + base + t);
        float4 q4 = *(const float4*)(pQT + base + t);
        float4 o;
        A += k4.x; o.x = q4.x / (A + 1e-6f);
        A += k4.y; o.y = q4.y / (A + 1e-6f);
        A += k4.z; o.z = q4.z / (A + 1e-6f);
        A += k4.w; o.w = q4.w / (A + 1e-6f);
        *(float4*)(pQT + base + t) = o;
    }
}

// K3: causal attention out = tril(Qw @ pK^T) @ V per n. 64-row tiles, 64-col
// chunks, K-dim (128) in two LDS halves. 4x4 register tiling, 256 threads.
__global__ __launch_bounds__(256) void k_attn(
    const float* __restrict__ qwT, const float* __restrict__ pKT,
    const float* __restrict__ Vhf, float* __restrict__ out)
{
    __shared__ float Qs[64 * 68];   // QwT half: [kk][i]
    __shared__ float Ks[64 * 68];   // KpT half: [kk][j]; later aliased as ST[t'][i]
    __shared__ float Vs[64 * 64];   // V chunk: [t'][d]

    const int rt = blockIdx.x, n = blockIdx.y;
    const int g = n >> 3, h = n & 7;
    const int tid = threadIdx.x;
    const int ty = tid >> 4, tx = tid & 15;

    float o[4][4] = {};
    for (int c = 0; c <= rt; ++c) {
        float acc[4][4] = {};
        for (int half = 0; half < 2; ++half) {
            __syncthreads();   // protect LDS from previous chunk's readers
#pragma unroll
            for (int m = 0; m < 16; ++m) {
                int idx = m * 256 + tid;
                int i = idx & 63, kk = idx >> 6;
                Qs[kk * 68 + i] = qwT[(long)(n * LR + half * 64 + kk) * T_LEN + rt * 64 + i];
                Ks[kk * 68 + i] = pKT[(long)(n * LR + half * 64 + kk) * T_LEN + c * 64 + i];
            }
            if (half == 0) {
#pragma unroll
                for (int m = 0; m < 16; ++m) {
                    int idx = m * 256 + tid;
                    int d = idx & 63, tq = idx >> 6;
                    Vs[tq * 64 + d] = Vhf[((long)(g * T_LEN + c * 64 + tq) * H_HEADS + h) * DK + d];
                }
            }
            __syncthreads();
#pragma unroll 8
            for (int kk = 0; kk < 64; ++kk) {
                float4 a4 = *(const float4*)(Qs + kk * 68 + ty * 4);
                float4 b4 = *(const float4*)(Ks + kk * 68 + tx * 4);
                float a[4] = {a4.x, a4.y, a4.z, a4.w};
                float b[4] = {b4.x, b4.y, b4.z, b4.w};
#pragma unroll
                for (int ii = 0; ii < 4; ++ii)
#pragma unroll
                    for (int jj = 0; jj < 4; ++jj) acc[ii][jj] += a[ii] * b[jj];
            }
        }
        if (c == rt) {   // causal mask on the diagonal chunk: keep t' <= t
#pragma unroll
            for (int ii = 0; ii < 4; ++ii)
#pragma unroll
                for (int jj = 0; jj < 4; ++jj)
                    if (tx * 4 + jj > ty * 4 + ii) acc[ii][jj] = 0.f;
        }
        __syncthreads();  // all reads of Ks done -> reuse as ST[t'][i]
#pragma unroll
        for (int jj = 0; jj < 4; ++jj) {
            float4 v = make_float4(acc[0][jj], acc[1][jj], acc[2][jj], acc[3][jj]);
            *(float4*)(Ks + (tx * 4 + jj) * 68 + ty * 4) = v;
        }
        __syncthreads();
#pragma unroll 8
        for (int kk = 0; kk < 64; ++kk) {
            float4 s4 = *(const float4*)(Ks + kk * 68 + ty * 4);
            float4 v4 = *(const float4*)(Vs + kk * 64 + tx * 4);
            float s[4] = {s4.x, s4.y, s4.z, s4.w};
            float v[4] = {v4.x, v4.y, v4.z, v4.w};
#pragma unroll
            for (int ii = 0; ii < 4; ++ii)
#pragma unroll
                for (int jj = 0; jj < 4; ++jj) o[ii][jj] += s[ii] * v[jj];
        }
    }
#pragma unroll
    for (int ii = 0; ii < 4; ++ii) {
        int t = rt * 64 + ty * 4 + ii;
        float4 v = make_float4(o[ii][0], o[ii][1], o[ii][2], o[ii][3]);
        *(float4*)(out + ((long)(g * T_LEN + t) * H_HEADS + h) * DK + tx * 4) = v;
    }
}

extern "C" void kernel_launch(void* const* d_in, const int* in_sizes, int n_in,
                              void* d_out, int out_size, void* d_ws, size_t ws_size,
                              hipStream_t stream) {
    const float* Khf     = (const float*)d_in[0];
    const float* Vhf     = (const float*)d_in[1];
    const float* Qhf     = (const float*)d_in[2];
    const float* planesT = (const float*)d_in[3];
    const float* protosT = (const float*)d_in[4];
    float* outp = (float*)d_out;

    float* pKT = (float*)d_ws;                            // [32][128][512]
    float* pQT = pKT + (size_t)NTOT * LR * T_LEN;         // [32][128][512] -> qw in place

    k_probs<<<dim3(256), dim3(256), 0, stream>>>(Khf, Qhf, planesT, protosT, pKT, pQT);
    k_cumsum<<<dim3(16), dim3(256), 0, stream>>>(pKT, pQT);
    k_attn<<<dim3(8, 32), dim3(256), 0, stream>>>(pQT, pKT, Vhf, outp);
}